// Round 11
// baseline (375.671 us; speedup 1.0000x reference)
//
#include <hip/hip_runtime.h>

typedef unsigned short u16;
typedef __attribute__((ext_vector_type(8))) short bf16x8;
typedef __attribute__((ext_vector_type(8))) unsigned short u16x8;
typedef __attribute__((ext_vector_type(4))) float f32x4;

// ---------- bf16 split helpers ----------
__device__ __forceinline__ u16 f2bf_rne(float f) {
  unsigned u = __float_as_uint(f);
  u += 0x7fffu + ((u >> 16) & 1u);
  return (u16)(u >> 16);
}
__device__ __forceinline__ float bf2f(u16 h) {
  return __uint_as_float(((unsigned)h) << 16);
}
__device__ __forceinline__ void split1(float v, u16& h, u16& l) {
  u16 hh = f2bf_rne(v);
  h = hh;
  l = f2bf_rne(v - bf2f(hh));
}

// ---------- global -> LDS async 16B ----------
__device__ __forceinline__ void gl16(const void* g, void* l) {
  __builtin_amdgcn_global_load_lds(
      (const __attribute__((address_space(1))) unsigned int*)g,
      (__attribute__((address_space(3))) unsigned int*)l,
      16, 0, 0);
}

// ---------- merged split-convert (x and Wqkv) ----------
__global__ void split_convert_all(const float4* __restrict__ x,
                                  ushort4* __restrict__ xhi, ushort4* __restrict__ xlo,
                                  const float4* __restrict__ wq,
                                  ushort4* __restrict__ wqh, ushort4* __restrict__ wql) {
  int i = blockIdx.x * 256 + threadIdx.x;
  const float4* src;
  ushort4 *dh, *dl;
  int idx;
  if (i < 3145728) { src = x; dh = xhi; dl = xlo; idx = i; }
  else if (i < 3588096) { src = wq; dh = wqh; dl = wql; idx = i - 3145728; }
  else return;
  float4 v = src[idx];
  ushort4 h, l;
  split1(v.x, h.x, l.x); split1(v.y, h.y, l.y);
  split1(v.z, h.z, l.z); split1(v.w, h.w, l.w);
  dh[idx] = h; dl[idx] = l;
}

// ---------- split-bf16 GEMM: C[M,N] = A[M,K] * B[N,K]^T ----------
// R16 GEMMs = R15 unchanged (GEMM1 writes qkv directly as bf16 hi/lo splits
// into 4608-stride row slots: hi at +n, lo at +2304+n).
// Closed axes (measured): sync-structure edits (R6/R7/R8), 32x32 shape (R9),
// BK=32 TLP (R10), cheaper split bases (R11), XCD swizzle (R12),
// A-from-global (R14). R15 lesson: split C-writes cost +7.5us in epilogue and
// write-amplify 2x (32B runs into 64B sectors across XCDs) — kept anyway
// because attn's halved read + better absmax offset it; do NOT expect
// WRITE_SIZE to halve.
// 3 MFMAs per fragment pair: hi*hi + hi*lo + lo*hi.
// LDS XOR swizzle: physical chunk p of row r holds logical chunk p ^ (r&7);
// 16-lane reader groups put exactly 2 lanes per bank-quad (2-way = free).
// A has explicit row stride lda (u16 elems) so GEMM2 reads the interleaved
// hi/lo rows written in-place into the qkv region. B stride = K.
// B2 pair: rows with 2*tm0 >= M use Bhi2/Blo2 (per-batch folded weights in GEMM2).
template <int BM, bool SPLIT>
__global__ __launch_bounds__(256, (BM == 128 ? 2 : 3)) void gemm_split_bt(
    const u16* __restrict__ Ahi, const u16* __restrict__ Alo, int lda,
    const u16* __restrict__ Bhi, const u16* __restrict__ Blo,
    const u16* __restrict__ Bhi2, const u16* __restrict__ Blo2,
    void* __restrict__ Cv, int M, int N, int K) {
  constexpr int MI = BM / 32;      // per-wave m 16-tiles (4 or 2)
  constexpr int AR = BM / 4;       // A rows staged per wave (32 or 16)
  constexpr int RA = AR / 8;       // A gl16 reps per array (4 or 2)
  __shared__ __align__(16) u16 sAh[BM * 64], sAl[BM * 64];
  __shared__ __align__(16) u16 sBh[128 * 64], sBl[128 * 64];
  const int tid = threadIdx.x;
  const int wave = tid >> 6;
  const int lane = tid & 63;
  const int tm0 = blockIdx.x * BM;
  const int tn0 = blockIdx.y * 128;
  const int wm = (wave & 1) * (BM / 2);
  const int wn = (wave >> 1) * 64;
  if (2 * tm0 >= M) { Bhi = Bhi2; Blo = Blo2; }

  // staging: 8 lanes/row (128 B/row), 8 rows per gl16, source chunk
  // pre-swizzled. A: RA gl16 per array (wave owns AR rows); B: 4 (32 rows).
  const int c = lane & 7;
  const int scol = (c ^ ((lane >> 3) & 7)) * 8;  // XOR-swizzled source chunk
  const int srowA = wave * AR + (lane >> 3);
  const int srowB = wave * 32 + (lane >> 3);
  const u16* gAh = Ahi + (size_t)(tm0 + srowA) * lda + scol;
  const u16* gAl = Alo + (size_t)(tm0 + srowA) * lda + scol;
  const u16* gBh = Bhi + (size_t)(tn0 + srowB) * K + scol;
  const u16* gBl = Blo + (size_t)(tn0 + srowB) * K + scol;
  u16* lAh = &sAh[wave * AR * 64];
  u16* lAl = &sAl[wave * AR * 64];
  u16* lBh = &sBh[wave * 32 * 64];
  u16* lBl = &sBl[wave * 32 * 64];
  const size_t rstepA = (size_t)8 * lda;  // 8 rows per gl16
  const size_t rstepB = (size_t)8 * K;

  f32x4 acc[MI][4] = {};
  const int fr = lane & 15;    // A/B fragment row (m or n within 16-tile)
  const int quad = lane >> 4;  // logical k-chunk within 32-k sub-block

  for (int kt = 0; kt < K; kt += 64) {
#pragma unroll
    for (int r = 0; r < 4; ++r) {
      if (r < RA) {
        gl16(gAh + kt + r * rstepA, lAh + r * 512);
        gl16(gAl + kt + r * rstepA, lAl + r * 512);
      }
      gl16(gBh + kt + r * rstepB, lBh + r * 512);
      gl16(gBl + kt + r * rstepB, lBl + r * 512);
    }
    __syncthreads();
    for (int subk = 0; subk < 2; ++subk) {
      const int k0 = ((subk * 4 + quad) ^ (fr & 7)) * 8;  // physical chunk * 8 u16
      bf16x8 ah[MI], al[MI], bh[4], bl[4];
#pragma unroll
      for (int i = 0; i < MI; ++i) {
        ah[i] = *(const bf16x8*)&sAh[(wm + i * 16 + fr) * 64 + k0];
        al[i] = *(const bf16x8*)&sAl[(wm + i * 16 + fr) * 64 + k0];
      }
#pragma unroll
      for (int j = 0; j < 4; ++j) {
        bh[j] = *(const bf16x8*)&sBh[(wn + j * 16 + fr) * 64 + k0];
        bl[j] = *(const bf16x8*)&sBl[(wn + j * 16 + fr) * 64 + k0];
      }
#pragma unroll
      for (int i = 0; i < MI; ++i)
#pragma unroll
        for (int j = 0; j < 4; ++j) {
          acc[i][j] = __builtin_amdgcn_mfma_f32_16x16x32_bf16(ah[i], bh[j], acc[i][j], 0, 0, 0);
          acc[i][j] = __builtin_amdgcn_mfma_f32_16x16x32_bf16(ah[i], bl[j], acc[i][j], 0, 0, 0);
          acc[i][j] = __builtin_amdgcn_mfma_f32_16x16x32_bf16(al[i], bh[j], acc[i][j], 0, 0, 0);
        }
    }
    __syncthreads();
  }

  // C/D layout: col = lane&15, row = (lane>>4)*4 + reg  (verified m89/m91)
  const int col = lane & 15;
  const int rowq = (lane >> 4) * 4;
  if (SPLIT) {
    // write bf16 hi/lo into 4608-stride row slots: hi at +n, lo at +2304+n
    u16* Cs = (u16*)Cv;
#pragma unroll
    for (int i = 0; i < MI; ++i)
#pragma unroll
      for (int j = 0; j < 4; ++j) {
        const int n = tn0 + wn + j * 16 + col;
        size_t base = (size_t)(tm0 + wm + i * 16 + rowq) * 4608 + n;
#pragma unroll
        for (int r = 0; r < 4; ++r) {
          u16 h, l;
          split1(acc[i][j][r], h, l);
          Cs[base + (size_t)r * 4608] = h;
          Cs[base + (size_t)r * 4608 + 2304] = l;
        }
      }
  } else {
    float* C = (float*)Cv;
#pragma unroll
    for (int i = 0; i < MI; ++i)
#pragma unroll
      for (int j = 0; j < 4; ++j) {
        size_t base = (size_t)(tm0 + wm + i * 16 + rowq) * N + (tn0 + wn + j * 16 + col);
#pragma unroll
        for (int r = 0; r < 4; ++r) C[base + (size_t)r * N] = acc[i][j][r];
      }
  }
}

// ---------- fused dilated attention, ONE WAVE PER (i0, b, head-pair) ----------
// R16: the monolithic 256-thread attn block (~118 us, 2.3x its BW floor) had
// 4 barrier phases at 25-81% lane idleness and 37 KB LDS (4 blocks/CU). The
// computation is separable by head: output cols h*64..h*64+63 depend only on
// head h's q,k,v and the branch-weight logic is per-head. Grid (2048, 2, 6):
// one 64-lane wave handles 2 heads x 4 tokens; 6.4 KB LDS; barriers are
// single-wave (near-free); score phase uses all 64 lanes (32 dots x 2 halves
// + shfl_xor combine).
// Reads split qkv (hi at +n, lo at +2304+n per 4608-stride slot). Writes the
// UNNORMALIZED o-splits into the V REGION of each slot: hi at +1536+c,
// lo at +3840+c (c = global col 0..767). Race-free under the head split:
// v cols of head h are read ONLY by head h's own wave, which holds them in
// LDS before writing; q/k lo regions are untouched. GEMM2 reads A at
// qk16+1536 (hi) / +3840 (lo), stride 4608.
__global__ __launch_bounds__(64) void attn_dilated(const u16* __restrict__ qks,
                                                   u16* __restrict__ qk16,
                                                   float* __restrict__ Spart) {
  __shared__ float f[1536];     // [j][seg][128]: seg 0=q, 1=k, 2=v (2 heads)
  __shared__ float sc[2][16];
  __shared__ float Aw[2][16];
  const int lane = threadIdx.x;
  const int i0 = blockIdx.x;    // 0..2047
  const int b = blockIdx.y;     // 0..1
  const int hp = blockIdx.z;    // 0..5: heads 2hp, 2hp+1
  const size_t rowbase = (size_t)b * 8192 + i0;

  // load: 4 rows x 3 segs x 16 chunks of 8 u16 (hi + paired lo), reconstruct
#pragma unroll
  for (int it = 0; it < 3; ++it) {
    int item = it * 64 + lane;  // 0..191
    int j = item / 48, rem = item - j * 48;
    int seg = rem >> 4, chunk = rem & 15;
    const u16* slot = qks + (rowbase + 2048 * j) * 4608;
    const u16* p = slot + seg * 768 + hp * 128 + chunk * 8;
    u16x8 h8 = *(const u16x8*)p;
    u16x8 l8 = *(const u16x8*)(p + 2304);
    float4 v0, v1;
    v0.x = bf2f(h8[0]) + bf2f(l8[0]);
    v0.y = bf2f(h8[1]) + bf2f(l8[1]);
    v0.z = bf2f(h8[2]) + bf2f(l8[2]);
    v0.w = bf2f(h8[3]) + bf2f(l8[3]);
    v1.x = bf2f(h8[4]) + bf2f(l8[4]);
    v1.y = bf2f(h8[5]) + bf2f(l8[5]);
    v1.z = bf2f(h8[6]) + bf2f(l8[6]);
    v1.w = bf2f(h8[7]) + bf2f(l8[7]);
    float* dst = &f[j * 384 + seg * 128 + chunk * 8];
    ((float4*)dst)[0] = v0;
    ((float4*)dst)[1] = v1;
  }
  __syncthreads();

  {  // scores: lane = half*32 + h*16 + j*4 + jp; dot over 32 elems, combine
    int half = lane >> 5, l5 = lane & 31;
    int h = l5 >> 4, j = (l5 >> 2) & 3, jp = l5 & 3;
    const float4* q = (const float4*)&f[j * 384 + h * 64 + half * 32];
    const float4* k = (const float4*)&f[jp * 384 + 128 + h * 64 + half * 32];
    float s = 0.f;
#pragma unroll
    for (int d = 0; d < 8; ++d) {
      float4 a = q[d], bb = k[d];
      s += a.x * bb.x + a.y * bb.y + a.z * bb.z + a.w * bb.w;
    }
    s += __shfl_xor(s, 32);
    if (half == 0) sc[h][(j << 2) | jp] = s * 0.125f;
  }
  __syncthreads();

  if (lane < 8) {  // combine branch weights (2 heads x 4 j)
    int h = lane >> 2, j = lane & 3;
    float s0 = sc[h][j * 4 + 0], s1 = sc[h][j * 4 + 1];
    float s2 = sc[h][j * 4 + 2], s3 = sc[h][j * 4 + 3];
    float m = fmaxf(fmaxf(s0, s1), fmaxf(s2, s3));
    float e0 = expf(s0 - m), e1 = expf(s1 - m), e2 = expf(s2 - m), e3 = expf(s3 - m);
    float inv = 1.f / (e0 + e1 + e2 + e3);
    float a[4] = {e0 * inv, e1 * inv, e2 * inv, e3 * inv};
    if ((i0 & 1) == 0) {
      int p = j ^ 2;
      float ss = sc[h][j * 4 + j], sx = sc[h][j * 4 + p];
      float mm = fmaxf(ss, sx);
      float es = expf(ss - mm), ex = expf(sx - mm);
      float iv = 1.f / (es + ex);
      a[j] += es * iv;
      a[p] += ex * iv;
    }
    if ((i0 & 3) == 0) a[j] += 1.f;
    Aw[h][j * 4 + 0] = a[0]; Aw[h][j * 4 + 1] = a[1];
    Aw[h][j * 4 + 2] = a[2]; Aw[h][j * 4 + 3] = a[3];
  }
  __syncthreads();

  float* sp = Spart + ((size_t)b * 64 + (i0 & 63)) * 768 + hp * 128;
#pragma unroll
  for (int it = 0; it < 2; ++it) {
    int cc = it * 64 + lane;    // 0..127 within the head pair
    int h = cc >> 6;
    float v0 = f[0 * 384 + 256 + cc];
    float v1 = f[1 * 384 + 256 + cc];
    float v2 = f[2 * 384 + 256 + cc];
    float v3 = f[3 * 384 + 256 + cc];
    float ps = 0.f;
#pragma unroll
    for (int j = 0; j < 4; ++j) {
      float v = 0.f;
      v = fmaf(Aw[h][(j << 2) | 0], v0, v);
      v = fmaf(Aw[h][(j << 2) | 1], v1, v);
      v = fmaf(Aw[h][(j << 2) | 2], v2, v);
      v = fmaf(Aw[h][(j << 2) | 3], v3, v);
      u16 h16, l16;
      split1(v, h16, l16);
      size_t base = (rowbase + 2048 * j) * 4608;  // u16 offset of row slot
      qk16[base + 1536 + hp * 128 + cc] = h16;    // o-hi into v-hi region
      qk16[base + 3840 + hp * 128 + cc] = l16;    // o-lo into v-lo region
      ps += v;
    }
    atomicAdd(&sp[cc], ps);
  }
}

// ---------- reduce 64 partial slots -> Sinv = 1/colsum ----------
__global__ void colred(const float* __restrict__ Spart, float* __restrict__ Sinv) {
  int i = blockIdx.x * 256 + threadIdx.x;  // 0..1535
  if (i >= 1536) return;
  int b = i / 768, c = i - b * 768;
  const float* p = Spart + (size_t)b * 64 * 768 + c;
  float s = 0.f;
#pragma unroll
  for (int g = 0; g < 64; ++g) s += p[g * 768];
  Sinv[i] = 1.0f / s;
}

// ---------- fold normalization into Wout: W_b[e,c] = Wout[e,c] * Sinv[b,c], split ----------
__global__ void scale_wout(const float4* __restrict__ Wout, const float* __restrict__ Sinv,
                           ushort4* __restrict__ wh0, ushort4* __restrict__ wl0,
                           ushort4* __restrict__ wh1, ushort4* __restrict__ wl1) {
  int i = blockIdx.x * 256 + threadIdx.x;  // 0..294911 (2 * 147456 float4)
  if (i >= 294912) return;
  int b = i / 147456;
  int r = i - b * 147456;           // float4 index within 768x768
  int c = (r % 192) * 4;            // column of first element
  const float* s = Sinv + b * 768 + c;
  float4 v = Wout[r];
  v.x *= s[0]; v.y *= s[1]; v.z *= s[2]; v.w *= s[3];
  ushort4 h, l;
  split1(v.x, h.x, l.x); split1(v.y, h.y, l.y);
  split1(v.z, h.z, l.z); split1(v.w, h.w, l.w);
  if (b == 0) { wh0[r] = h; wl0[r] = l; }
  else        { wh1[r] = h; wl1[r] = l; }
}

extern "C" void kernel_launch(void* const* d_in, const int* in_sizes, int n_in,
                              void* d_out, int out_size, void* d_ws, size_t ws_size,
                              hipStream_t stream) {
  (void)in_sizes; (void)n_in; (void)out_size; (void)ws_size;
  const float* x = (const float*)d_in[0];     // (2,8192,768)
  const float* Wqkv = (const float*)d_in[1];  // (2304,768)
  const float* Wout = (const float*)d_in[2];  // (768,768)
  float* out = (float*)d_out;                 // (2,8192,768) fp32 final result

  // workspace layout (bytes):
  //  [0, 151MB)       qkv split region: u16 row slots stride 4608
  //                   (GEMM1: qkv hi at +n, lo at +2304+n; attn overwrites the
  //                   v region with o: hi at +1536+c, lo at +3840+c)
  //  [151MB, +25MB)   xhi  -> after GEMM1: Spart(384K) + Sinv(6K) + W_b splits (4x1.15MB)
  //  [176MB, +25MB)   xlo  (free after GEMM1)
  //  [201MB, +7MB)    wqh, wql
  char* w = (char*)d_ws;
  u16* qk16 = (u16*)(w);
  size_t off = 150994944;
  u16* xhi = (u16*)(w + off);
  float* Spart = (float*)(w + off);              // 393,216 B (reuse of xhi)
  float* Sinv = (float*)(w + off + 393216);      // 6,144 B
  u16* wh0 = (u16*)(w + off + 400000);           // 1,179,648 B each
  u16* wl0 = (u16*)(w + off + 1579648);
  u16* wh1 = (u16*)(w + off + 2759296);
  u16* wl1 = (u16*)(w + off + 3938944);
  off += 25165824;
  u16* xlo = (u16*)(w + off); off += 25165824;
  u16* wqh = (u16*)(w + off); off += 3538944;
  u16* wql = (u16*)(w + off); off += 3538944;    // ~208 MB total (same as R4)

  // 1) split-convert x and Wqkv
  split_convert_all<<<dim3(14016), 256, 0, stream>>>(
      (const float4*)x, (ushort4*)xhi, (ushort4*)xlo,
      (const float4*)Wqkv, (ushort4*)wqh, (ushort4*)wql);

  // 2) qkv = x @ Wqkv^T (M=16384, N=2304, K=768), written DIRECTLY as bf16
  //    hi/lo splits into the 4608-stride row slots
  gemm_split_bt<128, true><<<dim3(128, 18), 256, 0, stream>>>(
      xhi, xlo, 768, wqh, wql, wqh, wql, qk16, 16384, 2304, 768);

  // 3) zero partial-sum slots (xhi free now), fused attention:
  //    one wave per (i0, b, head-pair); writes o-splits into the v region
  hipMemsetAsync(Spart, 0, 393216, stream);
  attn_dilated<<<dim3(2048, 2, 6), 64, 0, stream>>>(qk16, qk16, Spart);

  // 4) reduce partials -> Sinv
  colred<<<dim3(6), 256, 0, stream>>>(Spart, Sinv);

  // 5) fold 1/S into Wout per batch, split to bf16 hi/lo
  scale_wout<<<dim3(1152), 256, 0, stream>>>((const float4*)Wout, Sinv,
                                             (ushort4*)wh0, (ushort4*)wl0,
                                             (ushort4*)wh1, (ushort4*)wl1);

  // 6) out = no @ W_b^T   (M=16384, N=768, K=768; A = o-splits in the v region)
  //    BM=64: 1536 blocks at 3 blocks/CU = 2.0 full rounds (no 25% tail).
  gemm_split_bt<64, false><<<dim3(256, 6), 256, 0, stream>>>(
      qk16 + 1536, qk16 + 3840, 4608, wh0, wl0, wh1, wl1, out, 16384, 768, 768);
}

// Round 12
// 342.946 us; speedup vs baseline: 1.0954x; 1.0954x over previous
//
#include <hip/hip_runtime.h>

typedef unsigned short u16;
typedef __attribute__((ext_vector_type(8))) short bf16x8;
typedef __attribute__((ext_vector_type(4))) float f32x4;

// ---------- bf16 split helpers ----------
__device__ __forceinline__ u16 f2bf_rne(float f) {
  unsigned u = __float_as_uint(f);
  u += 0x7fffu + ((u >> 16) & 1u);
  return (u16)(u >> 16);
}
__device__ __forceinline__ float bf2f(u16 h) {
  return __uint_as_float(((unsigned)h) << 16);
}
__device__ __forceinline__ void split1(float v, u16& h, u16& l) {
  u16 hh = f2bf_rne(v);
  h = hh;
  l = f2bf_rne(v - bf2f(hh));
}

// ---------- global -> LDS async 16B ----------
__device__ __forceinline__ void gl16(const void* g, void* l) {
  __builtin_amdgcn_global_load_lds(
      (const __attribute__((address_space(1))) unsigned int*)g,
      (__attribute__((address_space(3))) unsigned int*)l,
      16, 0, 0);
}

// ---------- merged split-convert (x and Wqkv) ----------
__global__ void split_convert_all(const float4* __restrict__ x,
                                  ushort4* __restrict__ xhi, ushort4* __restrict__ xlo,
                                  const float4* __restrict__ wq,
                                  ushort4* __restrict__ wqh, ushort4* __restrict__ wql) {
  int i = blockIdx.x * 256 + threadIdx.x;
  const float4* src;
  ushort4 *dh, *dl;
  int idx;
  if (i < 3145728) { src = x; dh = xhi; dl = xlo; idx = i; }
  else if (i < 3588096) { src = wq; dh = wqh; dl = wql; idx = i - 3145728; }
  else return;
  float4 v = src[idx];
  ushort4 h, l;
  split1(v.x, h.x, l.x); split1(v.y, h.y, l.y);
  split1(v.z, h.z, l.z); split1(v.w, h.w, l.w);
  dh[idx] = h; dl[idx] = l;
}

// ---------- split-bf16 GEMM: C[M,N] = A[M,K] * B[N,K]^T ----------
// R17 = best-of composite. GEMM core = R13 EXACT (fp32 C writes; best measured
// 152.5 us GEMM1, 52% MfmaUtil, 0 conflicts). R15/R16 split-C epilogue dropped:
// hi+lo u16 = 4 B/elem = fp32 — there was never a byte saving, only +7.5 us
// epilogue cost (session arithmetic error, now corrected).
// template<AIL>: GEMM2 reads A from the head-pair-interleaved o-layout the new
// attn writes (per token row slot of 4608 u16: hi of logical col k at
// (k>>7)*256 + (k&127), lo at +128). Staged chunks are <=56 u16 into a 64-u16
// kt-window, so the remap is linear per window: ka = ((kt>>7)<<8) | (kt&64).
// LDS layout / fragment reads unchanged.
// Closed axes (measured): sync-structure edits (R6/R7/R8), 32x32 shape (R9),
// BK=32 TLP (R10), cheaper split bases (R11), XCD swizzle (R12),
// A-from-global (R14), split-C epilogue (R15). Cross-run noise is +/-5-13%
// on GEMM1 (R15 160 vs R16 180.6, identical code) — only large deltas count.
// 3 MFMAs per fragment pair: hi*hi + hi*lo + lo*hi.
// LDS XOR swizzle: physical chunk p of row r holds logical chunk p ^ (r&7);
// 16-lane reader groups put exactly 2 lanes per bank-quad (2-way = free).
// A has explicit row stride lda (u16 elems). B stride = K.
// B2 pair: rows with 2*tm0 >= M use Bhi2/Blo2 (per-batch folded weights in GEMM2).
template <int BM, bool AIL>
__global__ __launch_bounds__(256, (BM == 128 ? 2 : 3)) void gemm_split_bt(
    const u16* __restrict__ Ahi, const u16* __restrict__ Alo, int lda,
    const u16* __restrict__ Bhi, const u16* __restrict__ Blo,
    const u16* __restrict__ Bhi2, const u16* __restrict__ Blo2,
    float* __restrict__ C, int M, int N, int K) {
  constexpr int MI = BM / 32;      // per-wave m 16-tiles (4 or 2)
  constexpr int AR = BM / 4;       // A rows staged per wave (32 or 16)
  constexpr int RA = AR / 8;       // A gl16 reps per array (4 or 2)
  __shared__ __align__(16) u16 sAh[BM * 64], sAl[BM * 64];
  __shared__ __align__(16) u16 sBh[128 * 64], sBl[128 * 64];
  const int tid = threadIdx.x;
  const int wave = tid >> 6;
  const int lane = tid & 63;
  const int tm0 = blockIdx.x * BM;
  const int tn0 = blockIdx.y * 128;
  const int wm = (wave & 1) * (BM / 2);
  const int wn = (wave >> 1) * 64;
  if (2 * tm0 >= M) { Bhi = Bhi2; Blo = Blo2; }

  // staging: 8 lanes/row (128 B/row), 8 rows per gl16, source chunk
  // pre-swizzled. A: RA gl16 per array (wave owns AR rows); B: 4 (32 rows).
  const int c = lane & 7;
  const int scol = (c ^ ((lane >> 3) & 7)) * 8;  // XOR-swizzled source chunk
  const int srowA = wave * AR + (lane >> 3);
  const int srowB = wave * 32 + (lane >> 3);
  const u16* gAh = Ahi + (size_t)(tm0 + srowA) * lda + scol;
  const u16* gAl = Alo + (size_t)(tm0 + srowA) * lda + scol;
  const u16* gBh = Bhi + (size_t)(tn0 + srowB) * K + scol;
  const u16* gBl = Blo + (size_t)(tn0 + srowB) * K + scol;
  u16* lAh = &sAh[wave * AR * 64];
  u16* lAl = &sAl[wave * AR * 64];
  u16* lBh = &sBh[wave * 32 * 64];
  u16* lBl = &sBl[wave * 32 * 64];
  const size_t rstepA = (size_t)8 * lda;  // 8 rows per gl16
  const size_t rstepB = (size_t)8 * K;

  f32x4 acc[MI][4] = {};
  const int fr = lane & 15;    // A/B fragment row (m or n within 16-tile)
  const int quad = lane >> 4;  // logical k-chunk within 32-k sub-block

  for (int kt = 0; kt < K; kt += 64) {
    // physical A offset of this kt window (interleaved layout remap)
    const int ka = AIL ? (((kt >> 7) << 8) | (kt & 64)) : kt;
#pragma unroll
    for (int r = 0; r < 4; ++r) {
      if (r < RA) {
        gl16(gAh + ka + r * rstepA, lAh + r * 512);
        gl16(gAl + ka + r * rstepA, lAl + r * 512);
      }
      gl16(gBh + kt + r * rstepB, lBh + r * 512);
      gl16(gBl + kt + r * rstepB, lBl + r * 512);
    }
    __syncthreads();
    for (int subk = 0; subk < 2; ++subk) {
      const int k0 = ((subk * 4 + quad) ^ (fr & 7)) * 8;  // physical chunk * 8 u16
      bf16x8 ah[MI], al[MI], bh[4], bl[4];
#pragma unroll
      for (int i = 0; i < MI; ++i) {
        ah[i] = *(const bf16x8*)&sAh[(wm + i * 16 + fr) * 64 + k0];
        al[i] = *(const bf16x8*)&sAl[(wm + i * 16 + fr) * 64 + k0];
      }
#pragma unroll
      for (int j = 0; j < 4; ++j) {
        bh[j] = *(const bf16x8*)&sBh[(wn + j * 16 + fr) * 64 + k0];
        bl[j] = *(const bf16x8*)&sBl[(wn + j * 16 + fr) * 64 + k0];
      }
#pragma unroll
      for (int i = 0; i < MI; ++i)
#pragma unroll
        for (int j = 0; j < 4; ++j) {
          acc[i][j] = __builtin_amdgcn_mfma_f32_16x16x32_bf16(ah[i], bh[j], acc[i][j], 0, 0, 0);
          acc[i][j] = __builtin_amdgcn_mfma_f32_16x16x32_bf16(ah[i], bl[j], acc[i][j], 0, 0, 0);
          acc[i][j] = __builtin_amdgcn_mfma_f32_16x16x32_bf16(al[i], bh[j], acc[i][j], 0, 0, 0);
        }
    }
    __syncthreads();
  }

  // C/D layout: col = lane&15, row = (lane>>4)*4 + reg  (verified m89/m91)
  const int col = lane & 15;
  const int rowq = (lane >> 4) * 4;
#pragma unroll
  for (int i = 0; i < MI; ++i)
#pragma unroll
    for (int j = 0; j < 4; ++j) {
      size_t base = (size_t)(tm0 + wm + i * 16 + rowq) * N + (tn0 + wn + j * 16 + col);
#pragma unroll
      for (int r = 0; r < 4; ++r) C[base + (size_t)r * N] = acc[i][j][r];
    }
}

// ---------- fused dilated attention, ONE WAVE PER (i0, b, head-pair) ----------
// Reads fp32 qkv (stride 2304 f32/row: q [0,768), k [768,1536), v [1536,2304)).
// Block (i0,b,hp) touches ONLY columns hp*128..hp*128+127 of q, k, and v.
// Writes the UNNORMALIZED o-splits IN PLACE into its OWN q columns:
// u16 slot offset hp*256+cc (hi) and hp*256+128+cc (lo) alias exactly q f32
// cols hp*128..hp*128+127 -> race-free (no other block ever reads/writes those
// bytes; this block loads q before writing). GEMM2 reads this interleaved
// layout via the AIL remap (Ahi=slot base, Alo=+128, lda=4608 u16).
__global__ __launch_bounds__(64) void attn_dilated(const float* __restrict__ qkv,
                                                   u16* __restrict__ qk16,
                                                   float* __restrict__ Spart) {
  __shared__ float f[1536];     // [j][seg][128]: seg 0=q, 1=k, 2=v (2 heads)
  __shared__ float sc[2][16];
  __shared__ float Aw[2][16];
  const int lane = threadIdx.x;
  const int i0 = blockIdx.x;    // 0..2047
  const int b = blockIdx.y;     // 0..1
  const int hp = blockIdx.z;    // 0..5: heads 2hp, 2hp+1
  const size_t rowbase = (size_t)b * 8192 + i0;

  // load: 384 float4 items = 4 rows x 3 segs x 32 float4 (own 128 cols each)
#pragma unroll
  for (int it = 0; it < 6; ++it) {
    int item = it * 64 + lane;  // 0..383
    int j = item / 96, rem = item - j * 96;
    int seg = rem >> 5, c4 = rem & 31;
    const float* p = qkv + (rowbase + 2048 * j) * 2304 + seg * 768 + hp * 128 + c4 * 4;
    ((float4*)&f[j * 384 + seg * 128 + c4 * 4])[0] = *(const float4*)p;
  }
  __syncthreads();

  {  // scores: lane = half*32 + h*16 + j*4 + jp; dot over 32 elems, combine
    int half = lane >> 5, l5 = lane & 31;
    int h = l5 >> 4, j = (l5 >> 2) & 3, jp = l5 & 3;
    const float4* q = (const float4*)&f[j * 384 + h * 64 + half * 32];
    const float4* k = (const float4*)&f[jp * 384 + 128 + h * 64 + half * 32];
    float s = 0.f;
#pragma unroll
    for (int d = 0; d < 8; ++d) {
      float4 a = q[d], bb = k[d];
      s += a.x * bb.x + a.y * bb.y + a.z * bb.z + a.w * bb.w;
    }
    s += __shfl_xor(s, 32);
    if (half == 0) sc[h][(j << 2) | jp] = s * 0.125f;
  }
  __syncthreads();

  if (lane < 8) {  // combine branch weights (2 heads x 4 j)
    int h = lane >> 2, j = lane & 3;
    float s0 = sc[h][j * 4 + 0], s1 = sc[h][j * 4 + 1];
    float s2 = sc[h][j * 4 + 2], s3 = sc[h][j * 4 + 3];
    float m = fmaxf(fmaxf(s0, s1), fmaxf(s2, s3));
    float e0 = expf(s0 - m), e1 = expf(s1 - m), e2 = expf(s2 - m), e3 = expf(s3 - m);
    float inv = 1.f / (e0 + e1 + e2 + e3);
    float a[4] = {e0 * inv, e1 * inv, e2 * inv, e3 * inv};
    if ((i0 & 1) == 0) {
      int p = j ^ 2;
      float ss = sc[h][j * 4 + j], sx = sc[h][j * 4 + p];
      float mm = fmaxf(ss, sx);
      float es = expf(ss - mm), ex = expf(sx - mm);
      float iv = 1.f / (es + ex);
      a[j] += es * iv;
      a[p] += ex * iv;
    }
    if ((i0 & 3) == 0) a[j] += 1.f;
    Aw[h][j * 4 + 0] = a[0]; Aw[h][j * 4 + 1] = a[1];
    Aw[h][j * 4 + 2] = a[2]; Aw[h][j * 4 + 3] = a[3];
  }
  __syncthreads();

  float* sp = Spart + ((size_t)b * 64 + (i0 & 63)) * 768 + hp * 128;
#pragma unroll
  for (int it = 0; it < 2; ++it) {
    int cc = it * 64 + lane;    // 0..127 within the head pair
    int h = cc >> 6;
    float v0 = f[0 * 384 + 256 + cc];
    float v1 = f[1 * 384 + 256 + cc];
    float v2 = f[2 * 384 + 256 + cc];
    float v3 = f[3 * 384 + 256 + cc];
    float ps = 0.f;
#pragma unroll
    for (int j = 0; j < 4; ++j) {
      float v = 0.f;
      v = fmaf(Aw[h][(j << 2) | 0], v0, v);
      v = fmaf(Aw[h][(j << 2) | 1], v1, v);
      v = fmaf(Aw[h][(j << 2) | 2], v2, v);
      v = fmaf(Aw[h][(j << 2) | 3], v3, v);
      u16 h16, l16;
      split1(v, h16, l16);
      size_t base = (rowbase + 2048 * j) * 4608;  // u16 offset of row slot
      qk16[base + hp * 256 + cc] = h16;           // o-hi (own q cols)
      qk16[base + hp * 256 + 128 + cc] = l16;     // o-lo (own q cols)
      ps += v;
    }
    atomicAdd(&sp[cc], ps);
  }
}

// ---------- reduce 64 partial slots -> Sinv = 1/colsum ----------
__global__ void colred(const float* __restrict__ Spart, float* __restrict__ Sinv) {
  int i = blockIdx.x * 256 + threadIdx.x;  // 0..1535
  if (i >= 1536) return;
  int b = i / 768, c = i - b * 768;
  const float* p = Spart + (size_t)b * 64 * 768 + c;
  float s = 0.f;
#pragma unroll
  for (int g = 0; g < 64; ++g) s += p[g * 768];
  Sinv[i] = 1.0f / s;
}

// ---------- fold normalization into Wout: W_b[e,c] = Wout[e,c] * Sinv[b,c], split ----------
__global__ void scale_wout(const float4* __restrict__ Wout, const float* __restrict__ Sinv,
                           ushort4* __restrict__ wh0, ushort4* __restrict__ wl0,
                           ushort4* __restrict__ wh1, ushort4* __restrict__ wl1) {
  int i = blockIdx.x * 256 + threadIdx.x;  // 0..294911 (2 * 147456 float4)
  if (i >= 294912) return;
  int b = i / 147456;
  int r = i - b * 147456;           // float4 index within 768x768
  int c = (r % 192) * 4;            // column of first element
  const float* s = Sinv + b * 768 + c;
  float4 v = Wout[r];
  v.x *= s[0]; v.y *= s[1]; v.z *= s[2]; v.w *= s[3];
  ushort4 h, l;
  split1(v.x, h.x, l.x); split1(v.y, h.y, l.y);
  split1(v.z, h.z, l.z); split1(v.w, h.w, l.w);
  if (b == 0) { wh0[r] = h; wl0[r] = l; }
  else        { wh1[r] = h; wl1[r] = l; }
}

extern "C" void kernel_launch(void* const* d_in, const int* in_sizes, int n_in,
                              void* d_out, int out_size, void* d_ws, size_t ws_size,
                              hipStream_t stream) {
  (void)in_sizes; (void)n_in; (void)out_size; (void)ws_size;
  const float* x = (const float*)d_in[0];     // (2,8192,768)
  const float* Wqkv = (const float*)d_in[1];  // (2304,768)
  const float* Wout = (const float*)d_in[2];  // (768,768)
  float* out = (float*)d_out;                 // (2,8192,768) fp32 final result

  // workspace layout (bytes):
  //  [0, 151MB)       qkv fp32 (stride 2304 f32/row); attn overwrites each
  //                   row's q region with interleaved o-splits (u16, per
  //                   head-pair hp: hi at hp*256+c, lo at hp*256+128+c)
  //  [151MB, +25MB)   xhi  -> after GEMM1: Spart(384K) + Sinv(6K) + W_b splits (4x1.15MB)
  //  [176MB, +25MB)   xlo  (free after GEMM1)
  //  [201MB, +7MB)    wqh, wql
  char* w = (char*)d_ws;
  float* qkv = (float*)(w);
  u16* qk16 = (u16*)(w);
  size_t off = 150994944;
  u16* xhi = (u16*)(w + off);
  float* Spart = (float*)(w + off);              // 393,216 B (reuse of xhi)
  float* Sinv = (float*)(w + off + 393216);      // 6,144 B
  u16* wh0 = (u16*)(w + off + 400000);           // 1,179,648 B each
  u16* wl0 = (u16*)(w + off + 1579648);
  u16* wh1 = (u16*)(w + off + 2759296);
  u16* wl1 = (u16*)(w + off + 3938944);
  off += 25165824;
  u16* xlo = (u16*)(w + off); off += 25165824;
  u16* wqh = (u16*)(w + off); off += 3538944;
  u16* wql = (u16*)(w + off); off += 3538944;    // ~208 MB total (same as R4)

  // 1) split-convert x and Wqkv
  split_convert_all<<<dim3(14016), 256, 0, stream>>>(
      (const float4*)x, (ushort4*)xhi, (ushort4*)xlo,
      (const float4*)Wqkv, (ushort4*)wqh, (ushort4*)wql);

  // 2) qkv = x @ Wqkv^T (M=16384, N=2304, K=768), fp32 out (R13 proven config)
  gemm_split_bt<128, false><<<dim3(128, 18), 256, 0, stream>>>(
      xhi, xlo, 768, wqh, wql, wqh, wql, qkv, 16384, 2304, 768);

  // 3) zero partial-sum slots (xhi free now), fused attention:
  //    one wave per (i0, b, head-pair); o-splits into own q columns
  hipMemsetAsync(Spart, 0, 393216, stream);
  attn_dilated<<<dim3(2048, 2, 6), 64, 0, stream>>>(qkv, qk16, Spart);

  // 4) reduce partials -> Sinv
  colred<<<dim3(6), 256, 0, stream>>>(Spart, Sinv);

  // 5) fold 1/S into Wout per batch, split to bf16 hi/lo
  scale_wout<<<dim3(1152), 256, 0, stream>>>((const float4*)Wout, Sinv,
                                             (ushort4*)wh0, (ushort4*)wl0,
                                             (ushort4*)wh1, (ushort4*)wl1);

  // 6) out = no @ W_b^T (M=16384, N=768, K=768; A = interleaved o-splits in
  //    the q region, AIL remap; hi base = slot 0, lo base = +128)
  //    BM=64: 1536 blocks at 3 blocks/CU = 2.0 full rounds (no 25% tail).
  gemm_split_bt<64, true><<<dim3(256, 6), 256, 0, stream>>>(
      qk16, qk16 + 128, 4608, wh0, wl0, wh1, wl1, out, 16384, 768, 768);
}